// Round 5
// baseline (1429.230 us; speedup 1.0000x reference)
//
#include <hip/hip_runtime.h>

#define NROWS 131072
#define DIM   128
#define FFD   512
#define TSTEPS 4
#define NBLK  512
#define CHUNK 64
#define NCHUNK 4   // NROWS / (NBLK*CHUNK)
#define NSLOT 16
#define SH    136  // stride for 128-wide bf16 LDS tiles (16B-aligned rows)
#define SKV   72   // stride for 64-wide bf16 LDS tiles (KT/VT)

static_assert((long)NBLK * CHUNK * NCHUNK == NROWS, "grid/chunk mismatch");

typedef short          s8v   __attribute__((ext_vector_type(8)));
typedef float          f4v   __attribute__((ext_vector_type(4)));
typedef unsigned short u16x4 __attribute__((ext_vector_type(4)));

#define MFMA16(a,b,c) __builtin_amdgcn_mfma_f32_16x16x32_bf16((a),(b),(c),0,0,0)

__device__ __forceinline__ unsigned short f2bf(float f){
    unsigned u = __builtin_bit_cast(unsigned, f);
    u += 0x7FFFu + ((u >> 16) & 1u);   // round-to-nearest-even
    return (unsigned short)(u >> 16);
}
__device__ __forceinline__ float bf2f(unsigned short h){
    return __builtin_bit_cast(float, (unsigned)h << 16);
}
// Non-temporal float4 access via native ext-vector type.
__device__ __forceinline__ f4v ntload4(const float* p){
    return __builtin_nontemporal_load((const f4v*)p);
}
__device__ __forceinline__ void ntstore4(float* p, f4v v){
    __builtin_nontemporal_store(v, (f4v*)p);
}

// ---------------------------------------------------------------------------
// Kernel A: LN1 (split bf16), K/V projections, per-block partial KtV -> atomic slots.
// Weight arrays are replicated ncopy x; block uses copy (blockIdx & cmask) so
// the read hot-set spreads across L3 slices / per-XCD L2s.
// ---------------------------------------------------------------------------
__global__ __launch_bounds__(512, 4)
void kA(const float* __restrict__ x, const unsigned short* __restrict__ Kwp,
        const unsigned short* __restrict__ Vwp,
        const float* __restrict__ ga, const float* __restrict__ be,
        float* __restrict__ slots, int cmask)
{
    __shared__ unsigned short hh[64*SH];    // h1 bf16 hi  (64 rows x 128 cols)
    __shared__ unsigned short hl[64*SH];    // h1 bf16 lo
    __shared__ unsigned short KT[128*SKV];  // K^T bf16: KT[c][r] (128 x 64)
    __shared__ unsigned short VT[128*SKV];
    const int tid  = threadIdx.x;
    const int wv   = tid >> 6, lane = tid & 63;
    const int quad = lane >> 4, l15 = lane & 15;
    const int lp   = lane >> 3, lr = lane & 7;   // LN layout: 8 lanes/row x 16 cols
    const int myrow = wv*8 + lr;                 // LN row within chunk
    const int pc    = wv*16 + l15;               // proj col / KtV row

    const unsigned short* Kc = Kwp + (size_t)(blockIdx.x & cmask)*16384;
    const unsigned short* Vc = Vwp + (size_t)(blockIdx.x & cmask)*16384;

    f4v acc[8];  // wave wv owns KtV rows [wv*16, +16): 8 col-tiles
    #pragma unroll
    for (int i = 0; i < 8; ++i) acc[i] = (f4v){0.f,0.f,0.f,0.f};

    for (int ch = 0; ch < NCHUNK; ++ch) {
        const size_t r0 = ((size_t)blockIdx.x*NCHUNK + ch)*CHUNK;
        // --- LN1 straight from global (non-temporal), split bf16 into LDS ---
        {
            float v[16];
            #pragma unroll
            for (int j = 0; j < 4; ++j) {
                const f4v t = ntload4(x + (r0 + myrow)*DIM + lp*16 + j*4);
                v[j*4+0] = t[0]; v[j*4+1] = t[1]; v[j*4+2] = t[2]; v[j*4+3] = t[3];
            }
            float s = 0.f, q = 0.f;
            #pragma unroll
            for (int i = 0; i < 16; ++i) { s += v[i]; q += v[i]*v[i]; }
            #pragma unroll
            for (int o = 8; o < 64; o <<= 1) { s += __shfl_xor(s, o); q += __shfl_xor(q, o); }
            const float m  = s * (1.0f/128.0f);
            const float rs = rsqrtf(q * (1.0f/128.0f) - m*m + 1e-5f);
            unsigned short hi16[16], lo16[16];
            #pragma unroll
            for (int j = 0; j < 4; ++j) {
                const float4 g = *(const float4*)(ga + lp*16 + j*4);
                const float4 b = *(const float4*)(be + lp*16 + j*4);
                float hv0 = (v[j*4+0]-m)*rs*g.x + b.x;
                float hv1 = (v[j*4+1]-m)*rs*g.y + b.y;
                float hv2 = (v[j*4+2]-m)*rs*g.z + b.z;
                float hv3 = (v[j*4+3]-m)*rs*g.w + b.w;
                hi16[j*4+0] = f2bf(hv0); lo16[j*4+0] = f2bf(hv0 - bf2f(hi16[j*4+0]));
                hi16[j*4+1] = f2bf(hv1); lo16[j*4+1] = f2bf(hv1 - bf2f(hi16[j*4+1]));
                hi16[j*4+2] = f2bf(hv2); lo16[j*4+2] = f2bf(hv2 - bf2f(hi16[j*4+2]));
                hi16[j*4+3] = f2bf(hv3); lo16[j*4+3] = f2bf(hv3 - bf2f(hi16[j*4+3]));
            }
            #pragma unroll
            for (int j = 0; j < 2; ++j) {
                *(s8v*)&hh[myrow*SH + lp*16 + j*8] = *(const s8v*)&hi16[j*8];
                *(s8v*)&hl[myrow*SH + lp*16 + j*8] = *(const s8v*)&lo16[j*8];
            }
        }
        __syncthreads();
        // --- K and V projections: M=64, N=128, K=128; wave wv -> cols [wv*16,+16) ---
        #pragma unroll
        for (int p = 0; p < 2; ++p) {
            const unsigned short* Wp = p ? Vc : Kc;
            unsigned short* T = p ? VT : KT;
            s8v bf[4];
            #pragma unroll
            for (int ks = 0; ks < 4; ++ks)
                bf[ks] = *(const s8v*)(Wp + pc*DIM + ks*32 + quad*8);
            #pragma unroll
            for (int mt = 0; mt < 4; ++mt) {
                s8v ah[4], al[4];
                #pragma unroll
                for (int ks = 0; ks < 4; ++ks) {
                    ah[ks] = *(const s8v*)(&hh[(mt*16 + l15)*SH + ks*32 + quad*8]);
                    al[ks] = *(const s8v*)(&hl[(mt*16 + l15)*SH + ks*32 + quad*8]);
                }
                f4v c = {0.f,0.f,0.f,0.f};
                #pragma unroll
                for (int ks = 0; ks < 4; ++ks) c = MFMA16(ah[ks], bf[ks], c);
                #pragma unroll
                for (int ks = 0; ks < 4; ++ks) c = MFMA16(al[ks], bf[ks], c);
                // C layout: row=quad*4+reg, col=l15 -> store transposed T[col][row]
                u16x4 w4 = { f2bf(c[0]), f2bf(c[1]), f2bf(c[2]), f2bf(c[3]) };
                *(u16x4*)&T[pc*SKV + mt*16 + quad*4] = w4;
            }
        }
        __syncthreads();
        // --- KtV += K_chunk^T @ V_chunk: M=128(i), N=128(j), K=64(rows) ---
        #pragma unroll
        for (int ks = 0; ks < 2; ++ks) {
            const s8v af = *(const s8v*)(&KT[pc*SKV + ks*32 + quad*8]);
            #pragma unroll
            for (int jt = 0; jt < 8; ++jt) {
                const s8v bfr = *(const s8v*)(&VT[(jt*16 + l15)*SKV + ks*32 + quad*8]);
                acc[jt] = MFMA16(af, bfr, acc[jt]);
            }
        }
        __syncthreads();
    }
    // --- accumulate partial KtV into one of NSLOT slots (fp32 atomics) ---
    float* S = slots + (size_t)(blockIdx.x & (NSLOT-1)) * 16384;
    #pragma unroll
    for (int jt = 0; jt < 8; ++jt) {
        const int i0 = wv*16 + quad*4;
        const int j  = jt*16 + l15;
        #pragma unroll
        for (int rg = 0; rg < 4; ++rg)
            atomicAdd(&S[(i0 + rg)*DIM + j], acc[jt][rg]);
    }
}

// Reduce NSLOT partial KtV matrices -> ktv (fp32, 128x128)
__global__ void kReduce(const float* __restrict__ slots, float* __restrict__ ktv)
{
    const int e = blockIdx.x*256 + threadIdx.x;  // 16384 threads
    float s = 0.f;
    #pragma unroll
    for (int b = 0; b < NSLOT; ++b) s += slots[(size_t)b*16384 + e];
    ktv[e] = s;
}

// M = Qw @ KtV (fp32), packed split bf16 as Mp/Ml[j][k] (B-operand [n][k] layout),
// replicated ncopy x.
__global__ void kBuildM(const float* __restrict__ Qw, const float* __restrict__ ktv,
                        unsigned short* __restrict__ Mp, unsigned short* __restrict__ Ml,
                        int ncopy)
{
    const int idx = blockIdx.x*256 + threadIdx.x;  // 16384
    const int j = idx >> 7, k = idx & 127;
    float s = 0.f;
    for (int i = 0; i < 128; ++i) s += Qw[k*128 + i] * ktv[i*128 + j];
    const unsigned short hi = f2bf(s);
    const unsigned short lo = f2bf(s - bf2f(hi));
    for (int c = 0; c < ncopy; ++c) {
        Mp[(size_t)c*16384 + idx] = hi;
        Ml[(size_t)c*16384 + idx] = lo;
    }
}

// ---------------------------------------------------------------------------
// Kernel B: x += h1 @ M ; LN2 ; x += relu(h2@w1+b1)@w2 + b2   (in-place safe)
// 8 waves / 512 threads; wave wv owns output cols [wv*16,+16).
// Weight/M arrays replicated; block uses copy (blockIdx & cmask).
// ---------------------------------------------------------------------------
__global__ __launch_bounds__(512, 4)
void kB(const float* __restrict__ xin, float* __restrict__ xout,
        const unsigned short* __restrict__ Mp, const unsigned short* __restrict__ Ml,
        const float* __restrict__ g1a, const float* __restrict__ b1a,
        const float* __restrict__ g2a, const float* __restrict__ b2a,
        const unsigned short* __restrict__ w1p, const float* __restrict__ fb1,
        const unsigned short* __restrict__ w2p, const float* __restrict__ fb2,
        int cmask)
{
    __shared__ float          xb[64*132];  // fp32 residual tile, stride 132
    __shared__ unsigned short hs[64*SH];   // bf16 LN output (hi)
    __shared__ unsigned short fbuf[64*SH]; // bf16 relu(ff) quarter; doubles as h1-lo
    unsigned short* const hl = fbuf;
    const int tid  = threadIdx.x;
    const int wv   = tid >> 6, lane = tid & 63;
    const int quad = lane >> 4, l15 = lane & 15;
    const int lp   = lane >> 3, lr = lane & 7;
    const int myrow = wv*8 + lr;         // LN row within chunk
    const int cg    = wv*16 + l15;       // GEMM output col

    const unsigned short* Mc  = Mp  + (size_t)(blockIdx.x & cmask)*16384;
    const unsigned short* Mlc = Ml  + (size_t)(blockIdx.x & cmask)*16384;
    const unsigned short* w1c = w1p + (size_t)(blockIdx.x & cmask)*65536;
    const unsigned short* w2c = w2p + (size_t)(blockIdx.x & cmask)*65536;

    for (int ch = 0; ch < NCHUNK; ++ch) {
        const size_t r0 = ((size_t)blockIdx.x*NCHUNK + ch)*CHUNK;
        // --- stage x chunk into LDS (coalesced non-temporal float4) ---
        #pragma unroll
        for (int i = 0; i < 4; ++i) {
            const int idx = tid + i*512;          // float4 index; 32 per row
            const int r = idx >> 5, c = (idx & 31)*4;
            const f4v t = ntload4(xin + (r0 + r)*DIM + c);
            *(f4v*)&xb[r*132 + c] = t;
        }
        __syncthreads();
        // --- LN1 (split), 16 elems/lane ---
        {
            float v[16];
            #pragma unroll
            for (int j = 0; j < 4; ++j)
                *(float4*)&v[j*4] = *(const float4*)&xb[myrow*132 + lp*16 + j*4];
            float s = 0.f, q = 0.f;
            #pragma unroll
            for (int i = 0; i < 16; ++i) { s += v[i]; q += v[i]*v[i]; }
            #pragma unroll
            for (int o = 8; o < 64; o <<= 1) { s += __shfl_xor(s, o); q += __shfl_xor(q, o); }
            const float m  = s * (1.0f/128.0f);
            const float rs = rsqrtf(q * (1.0f/128.0f) - m*m + 1e-5f);
            unsigned short hi16[16], lo16[16];
            #pragma unroll
            for (int j = 0; j < 4; ++j) {
                const float4 g = *(const float4*)(g1a + lp*16 + j*4);
                const float4 b = *(const float4*)(b1a + lp*16 + j*4);
                float hv0 = (v[j*4+0]-m)*rs*g.x + b.x;
                float hv1 = (v[j*4+1]-m)*rs*g.y + b.y;
                float hv2 = (v[j*4+2]-m)*rs*g.z + b.z;
                float hv3 = (v[j*4+3]-m)*rs*g.w + b.w;
                hi16[j*4+0] = f2bf(hv0); lo16[j*4+0] = f2bf(hv0 - bf2f(hi16[j*4+0]));
                hi16[j*4+1] = f2bf(hv1); lo16[j*4+1] = f2bf(hv1 - bf2f(hi16[j*4+1]));
                hi16[j*4+2] = f2bf(hv2); lo16[j*4+2] = f2bf(hv2 - bf2f(hi16[j*4+2]));
                hi16[j*4+3] = f2bf(hv3); lo16[j*4+3] = f2bf(hv3 - bf2f(hi16[j*4+3]));
            }
            #pragma unroll
            for (int j = 0; j < 2; ++j) {
                *(s8v*)&hs[myrow*SH + lp*16 + j*8] = *(const s8v*)&hi16[j*8];
                *(s8v*)&hl[myrow*SH + lp*16 + j*8] = *(const s8v*)&lo16[j*8];
            }
        }
        __syncthreads();
        // --- GEMM1: dx = h1 @ M (3-way split: Ah*Mh + Ah*Ml + Al*Mh) ---
        {
            s8v bh[4], bl[4];
            #pragma unroll
            for (int ks = 0; ks < 4; ++ks) {
                bh[ks] = *(const s8v*)(Mc  + cg*DIM + ks*32 + quad*8);
                bl[ks] = *(const s8v*)(Mlc + cg*DIM + ks*32 + quad*8);
            }
            #pragma unroll
            for (int mt = 0; mt < 4; ++mt) {
                s8v ah[4], al[4];
                #pragma unroll
                for (int ks = 0; ks < 4; ++ks) {
                    ah[ks] = *(const s8v*)(&hs[(mt*16 + l15)*SH + ks*32 + quad*8]);
                    al[ks] = *(const s8v*)(&hl[(mt*16 + l15)*SH + ks*32 + quad*8]);
                }
                f4v c = {0.f,0.f,0.f,0.f};
                #pragma unroll
                for (int ks = 0; ks < 4; ++ks) c = MFMA16(ah[ks], bh[ks], c);
                #pragma unroll
                for (int ks = 0; ks < 4; ++ks) c = MFMA16(ah[ks], bl[ks], c);
                #pragma unroll
                for (int ks = 0; ks < 4; ++ks) c = MFMA16(al[ks], bh[ks], c);
                #pragma unroll
                for (int rg = 0; rg < 4; ++rg)
                    xb[(mt*16 + quad*4 + rg)*132 + cg] += c[rg];
            }
        }
        __syncthreads();
        // --- LN2 (hi only), 16 elems/lane ---
        {
            float v[16];
            #pragma unroll
            for (int j = 0; j < 4; ++j)
                *(float4*)&v[j*4] = *(const float4*)&xb[myrow*132 + lp*16 + j*4];
            float s = 0.f, q = 0.f;
            #pragma unroll
            for (int i = 0; i < 16; ++i) { s += v[i]; q += v[i]*v[i]; }
            #pragma unroll
            for (int o = 8; o < 64; o <<= 1) { s += __shfl_xor(s, o); q += __shfl_xor(q, o); }
            const float m  = s * (1.0f/128.0f);
            const float rs = rsqrtf(q * (1.0f/128.0f) - m*m + 1e-5f);
            unsigned short hi16[16];
            #pragma unroll
            for (int j = 0; j < 4; ++j) {
                const float4 g = *(const float4*)(g2a + lp*16 + j*4);
                const float4 b = *(const float4*)(b2a + lp*16 + j*4);
                hi16[j*4+0] = f2bf((v[j*4+0]-m)*rs*g.x + b.x);
                hi16[j*4+1] = f2bf((v[j*4+1]-m)*rs*g.y + b.y);
                hi16[j*4+2] = f2bf((v[j*4+2]-m)*rs*g.z + b.z);
                hi16[j*4+3] = f2bf((v[j*4+3]-m)*rs*g.w + b.w);
            }
            #pragma unroll
            for (int j = 0; j < 2; ++j)
                *(s8v*)&hs[myrow*SH + lp*16 + j*8] = *(const s8v*)&hi16[j*8];
        }
        __syncthreads();
        // --- FF: four quarters of 128 ff-cols; dx2 accumulated across quarters ---
        f4v dx2[4];
        #pragma unroll
        for (int i = 0; i < 4; ++i) dx2[i] = (f4v){0.f,0.f,0.f,0.f};
        #pragma unroll
        for (int qf = 0; qf < 4; ++qf) {
            // GEMM2a: f = relu(h2 @ w1[:, quarter] + b1); wave wv -> local cols [wv*16,+16)
            const int ffc = qf*128 + cg;
            s8v wa[4];
            #pragma unroll
            for (int ks = 0; ks < 4; ++ks)
                wa[ks] = *(const s8v*)(w1c + ffc*DIM + ks*32 + quad*8);
            const float bias = fb1[ffc];
            #pragma unroll
            for (int mt = 0; mt < 4; ++mt) {
                s8v af[4];
                #pragma unroll
                for (int ks = 0; ks < 4; ++ks)
                    af[ks] = *(const s8v*)(&hs[(mt*16 + l15)*SH + ks*32 + quad*8]);
                f4v c = {0.f,0.f,0.f,0.f};
                #pragma unroll
                for (int ks = 0; ks < 4; ++ks) c = MFMA16(af[ks], wa[ks], c);
                #pragma unroll
                for (int rg = 0; rg < 4; ++rg) {
                    float vv = c[rg] + bias;
                    vv = vv > 0.f ? vv : 0.f;
                    fbuf[(mt*16 + quad*4 + rg)*SH + cg] = f2bf(vv);
                }
            }
            __syncthreads();
            // GEMM2b: dx2 += f @ w2[quarter, :]; wave wv -> cols [wv*16,+16)
            s8v wb[4];
            #pragma unroll
            for (int ks = 0; ks < 4; ++ks)
                wb[ks] = *(const s8v*)(w2c + cg*FFD + qf*128 + ks*32 + quad*8);
            #pragma unroll
            for (int mt = 0; mt < 4; ++mt) {
                s8v af[4];
                #pragma unroll
                for (int ks = 0; ks < 4; ++ks)
                    af[ks] = *(const s8v*)(&fbuf[(mt*16 + l15)*SH + ks*32 + quad*8]);
                f4v c = dx2[mt];
                #pragma unroll
                for (int ks = 0; ks < 4; ++ks) c = MFMA16(af[ks], wb[ks], c);
                dx2[mt] = c;
            }
            __syncthreads();
        }
        // --- epilogue: xb += dx2 + b2 ---
        {
            const float bias = fb2[cg];
            #pragma unroll
            for (int mt = 0; mt < 4; ++mt)
                #pragma unroll
                for (int rg = 0; rg < 4; ++rg)
                    xb[(mt*16 + quad*4 + rg)*132 + cg] += dx2[mt][rg] + bias;
        }
        __syncthreads();
        // --- coalesced non-temporal store (in-place safe) ---
        #pragma unroll
        for (int i = 0; i < 4; ++i) {
            const int idx = tid + i*512;
            const int r = idx >> 5, c = (idx & 31)*4;
            ntstore4(xout + (r0 + r)*DIM + c, *(const f4v*)&xb[r*132 + c]);
        }
        __syncthreads();
    }
}

// ---------------------------------------------------------------------------
// Final: out = x @ out_w + out_b  (split-x, in-place safe on d_out)
// ---------------------------------------------------------------------------
__global__ __launch_bounds__(256, 2)
void kF(const float* __restrict__ x, const unsigned short* __restrict__ Owp,
        const float* __restrict__ ob, float* __restrict__ out, int cmask)
{
    __shared__ unsigned short hh[64*SH];
    __shared__ unsigned short hl[64*SH];
    __shared__ float          xb[64*132];
    const int tid  = threadIdx.x;
    const int quad = (tid & 63) >> 4, l15 = tid & 15;

    const unsigned short* Oc = Owp + (size_t)(blockIdx.x & cmask)*16384;

    for (int ch = 0; ch < NCHUNK; ++ch) {
        const size_t r0 = ((size_t)blockIdx.x*NCHUNK + ch)*CHUNK;
        #pragma unroll
        for (int i = 0; i < 8; ++i) {
            const int idx = tid + i*256;
            const int r = idx >> 5, c = (idx & 31)*4;
            const f4v v = ntload4(x + (r0 + r)*DIM + c);
            const unsigned short h0 = f2bf(v[0]), h1 = f2bf(v[1]),
                                 h2 = f2bf(v[2]), h3 = f2bf(v[3]);
            u16x4 w4 = { h0, h1, h2, h3 };
            u16x4 l4 = { f2bf(v[0] - bf2f(h0)), f2bf(v[1] - bf2f(h1)),
                         f2bf(v[2] - bf2f(h2)), f2bf(v[3] - bf2f(h3)) };
            *(u16x4*)&hh[r*SH + c] = w4;
            *(u16x4*)&hl[r*SH + c] = l4;
        }
        __syncthreads();
        {
            const int wv_ = tid >> 6;
            s8v bf[2][4];
            #pragma unroll
            for (int nt = 0; nt < 2; ++nt)
                #pragma unroll
                for (int ks = 0; ks < 4; ++ks)
                    bf[nt][ks] = *(const s8v*)(Oc + (wv_*32 + nt*16 + l15)*DIM + ks*32 + quad*8);
            #pragma unroll
            for (int mt = 0; mt < 4; ++mt) {
                s8v ah[4], al[4];
                #pragma unroll
                for (int ks = 0; ks < 4; ++ks) {
                    ah[ks] = *(const s8v*)(&hh[(mt*16 + l15)*SH + ks*32 + quad*8]);
                    al[ks] = *(const s8v*)(&hl[(mt*16 + l15)*SH + ks*32 + quad*8]);
                }
                #pragma unroll
                for (int nt = 0; nt < 2; ++nt) {
                    f4v c = {0.f,0.f,0.f,0.f};
                    #pragma unroll
                    for (int ks = 0; ks < 4; ++ks) c = MFMA16(ah[ks], bf[nt][ks], c);
                    #pragma unroll
                    for (int ks = 0; ks < 4; ++ks) c = MFMA16(al[ks], bf[nt][ks], c);
                    const int cg = wv_*32 + nt*16 + l15;
                    const float bias = ob[cg];
                    #pragma unroll
                    for (int rg = 0; rg < 4; ++rg)
                        xb[(mt*16 + quad*4 + rg)*132 + cg] = c[rg] + bias;
                }
            }
        }
        __syncthreads();
        #pragma unroll
        for (int i = 0; i < 8; ++i) {
            const int idx = tid + i*256;
            const int r = idx >> 5, c = (idx & 31)*4;
            ntstore4(out + (r0 + r)*DIM + c, *(const f4v*)&xb[r*132 + c]);
        }
        __syncthreads();
    }
}

// Pack weights to bf16, transposed to B-operand [n][k] layout, replicated ncopy x.
__global__ void kPack(const float* __restrict__ Kw, const float* __restrict__ Vw,
                      const float* __restrict__ Ow, const float* __restrict__ w1,
                      const float* __restrict__ w2,
                      unsigned short* __restrict__ Kwp, unsigned short* __restrict__ Vwp,
                      unsigned short* __restrict__ Owp, unsigned short* __restrict__ w1p,
                      unsigned short* __restrict__ w2p, int ncopy)
{
    const int t = blockIdx.x*256 + threadIdx.x;  // 147456 total
    if (t < 16384) {
        const int n = t >> 7, k = t & 127;
        const unsigned short kv = f2bf(Kw[k*128 + n]);
        const unsigned short vv = f2bf(Vw[k*128 + n]);
        const unsigned short ov = f2bf(Ow[k*128 + n]);
        for (int c = 0; c < ncopy; ++c) {
            Kwp[(size_t)c*16384 + t] = kv;
            Vwp[(size_t)c*16384 + t] = vv;
            Owp[(size_t)c*16384 + t] = ov;
        }
    } else if (t < 16384 + 65536) {
        const int u = t - 16384;
        const int n = u >> 7, k = u & 127;      // w1: [128][512] -> w1p[n<512][k<128]
        const unsigned short v = f2bf(w1[k*FFD + n]);
        for (int c = 0; c < ncopy; ++c) w1p[(size_t)c*65536 + u] = v;
    } else {
        const int u = t - 16384 - 65536;
        const int n = u >> 9, k = u & 511;      // w2: [512][128] -> w2p[n<128][k<512]
        const unsigned short v = f2bf(w2[k*DIM + n]);
        for (int c = 0; c < ncopy; ++c) w2p[(size_t)c*65536 + u] = v;
    }
}

extern "C" void kernel_launch(void* const* d_in, const int* in_sizes, int n_in,
                              void* d_out, int out_size, void* d_ws, size_t ws_size,
                              hipStream_t stream)
{
    (void)in_sizes; (void)n_in; (void)out_size;
    const float* x_in = (const float*)d_in[0];
    const float* Kw   = (const float*)d_in[1];
    const float* Qw   = (const float*)d_in[2];
    const float* Vw   = (const float*)d_in[3];
    const float* ln1g = (const float*)d_in[4];
    const float* ln1b = (const float*)d_in[5];
    const float* ln2g = (const float*)d_in[6];
    const float* ln2b = (const float*)d_in[7];
    const float* w1   = (const float*)d_in[8];
    const float* b1   = (const float*)d_in[9];
    const float* w2   = (const float*)d_in[10];
    const float* b2   = (const float*)d_in[11];
    const float* Ow   = (const float*)d_in[12];
    const float* ob   = (const float*)d_in[13];

    // Workspace: slots + ktv + ncopy replicas of the packed weight/M arrays.
    // ncopy=8 spreads the read hot-set across XCDs (blockIdx & 7 ~ XCD id);
    // degrades to fewer copies if ws_size is tight (ncopy=1 == old layout).
    const size_t fixed_bytes  = (size_t)NSLOT*16384*4 + 16384*4;
    const size_t percopy_us   = 16384*3 + 65536*2 + 16384*2;  // ushorts per copy
    int ncopy = 8;
    while (ncopy > 1 && (ws_size != 0) &&
           fixed_bytes + percopy_us*2*(size_t)ncopy > ws_size) ncopy >>= 1;
    if (ws_size == 0) ncopy = 1;  // unknown workspace size: be conservative
    const int cmask = ncopy - 1;

    char* p = (char*)d_ws;
    float* slots        = (float*)p;          p += (size_t)NSLOT*16384*4;
    float* ktv          = (float*)p;          p += 16384*4;
    unsigned short* Kwp = (unsigned short*)p; p += (size_t)ncopy*16384*2;
    unsigned short* Vwp = (unsigned short*)p; p += (size_t)ncopy*16384*2;
    unsigned short* Owp = (unsigned short*)p; p += (size_t)ncopy*16384*2;
    unsigned short* w1p = (unsigned short*)p; p += (size_t)ncopy*65536*2;
    unsigned short* w2p = (unsigned short*)p; p += (size_t)ncopy*65536*2;
    unsigned short* Mp  = (unsigned short*)p; p += (size_t)ncopy*16384*2;
    unsigned short* Ml  = (unsigned short*)p; p += (size_t)ncopy*16384*2;

    float* X = (float*)d_out;   // 131072 x 128 fp32 working buffer == output buffer

    kPack<<<576, 256, 0, stream>>>(Kw, Vw, Ow, w1, w2, Kwp, Vwp, Owp, w1p, w2p, ncopy);

    const float* src = x_in;
    for (int t = 0; t < TSTEPS; ++t) {
        hipMemsetAsync(slots, 0, (size_t)NSLOT*16384*4, stream);
        kA<<<NBLK, 512, 0, stream>>>(src, Kwp, Vwp, ln1g, ln1b, slots, cmask);
        kReduce<<<64, 256, 0, stream>>>(slots, ktv);
        kBuildM<<<64, 256, 0, stream>>>(Qw, ktv, Mp, Ml, ncopy);
        kB<<<NBLK, 512, 0, stream>>>(src, X, Mp, Ml, ln1g, ln1b, ln2g, ln2b,
                                     w1p, b1, w2p, b2, cmask);
        src = X;
    }
    kF<<<NBLK, 256, 0, stream>>>(X, Owp, ob, (float*)d_out, cmask);
}

// Round 6
// 1194.947 us; speedup vs baseline: 1.1961x; 1.1961x over previous
//
#include <hip/hip_runtime.h>

#define NROWS 131072
#define DIM   128
#define FFD   512
#define TSTEPS 4
#define NBLK  512
#define CHUNK 128
#define NCHUNK 2   // NROWS / (NBLK*CHUNK)
#define NSLOT 16
#define SH    136  // stride for 128-wide bf16 LDS tiles (16B-aligned rows)

static_assert((long)NBLK * CHUNK * NCHUNK == NROWS, "grid/chunk mismatch");

typedef short          s8v   __attribute__((ext_vector_type(8)));
typedef float          f4v   __attribute__((ext_vector_type(4)));
typedef unsigned short u16x4 __attribute__((ext_vector_type(4)));

#define MFMA16(a,b,c) __builtin_amdgcn_mfma_f32_16x16x32_bf16((a),(b),(c),0,0,0)

__device__ __forceinline__ unsigned short f2bf(float f){
    unsigned u = __builtin_bit_cast(unsigned, f);
    u += 0x7FFFu + ((u >> 16) & 1u);   // round-to-nearest-even
    return (unsigned short)(u >> 16);
}
__device__ __forceinline__ float bf2f(unsigned short h){
    return __builtin_bit_cast(float, (unsigned)h << 16);
}
// Non-temporal float4 access via native ext-vector type (x is stream data).
__device__ __forceinline__ f4v ntload4(const float* p){
    return __builtin_nontemporal_load((const f4v*)p);
}
__device__ __forceinline__ void ntstore4(float* p, f4v v){
    __builtin_nontemporal_store(v, (f4v*)p);
}

// ---------------------------------------------------------------------------
// Kernel A: LN1 (split bf16), K/V projections, per-block partial KtV -> atomic slots.
// CHUNK=128 rows/chunk, 2 chunks/block: weight fragments loaded ONCE per block
// (hoisted out of the chunk loop) -> Kwp/Vwp global traffic 128 MB -> 33 MB.
// LDS 139 KB -> 1 block/CU, 8 waves.
// ---------------------------------------------------------------------------
__global__ __launch_bounds__(512, 2)
void kA(const float* __restrict__ x, const unsigned short* __restrict__ Kwp,
        const unsigned short* __restrict__ Vwp,
        const float* __restrict__ ga, const float* __restrict__ be,
        float* __restrict__ slots)
{
    __shared__ unsigned short hh[128*SH];   // h1 bf16 hi  (128 rows x 128 cols)
    __shared__ unsigned short hl[128*SH];   // h1 bf16 lo
    __shared__ unsigned short KT[128*SH];   // K^T bf16: KT[c][r] (128 cols x 128 rows)
    __shared__ unsigned short VT[128*SH];
    const int tid  = threadIdx.x;
    const int wv   = tid >> 6, lane = tid & 63;
    const int quad = lane >> 4, l15 = lane & 15;
    const int lp   = lane >> 3, lr = lane & 7;   // LN layout: 8 lanes/row x 16 cols
    const int myrow = wv*8 + lr;                 // LN row (0..63), 2 passes cover 128
    const int pc    = wv*16 + l15;               // proj col / KtV row (0..127)

    // --- weight fragments: loaded once per block, live in registers ---
    s8v bfK[4], bfV[4];
    #pragma unroll
    for (int ks = 0; ks < 4; ++ks) {
        bfK[ks] = *(const s8v*)(Kwp + pc*DIM + ks*32 + quad*8);
        bfV[ks] = *(const s8v*)(Vwp + pc*DIM + ks*32 + quad*8);
    }

    f4v acc[8];  // wave wv owns KtV rows [wv*16, +16): 8 col-tiles
    #pragma unroll
    for (int i = 0; i < 8; ++i) acc[i] = (f4v){0.f,0.f,0.f,0.f};

    for (int ch = 0; ch < NCHUNK; ++ch) {
        const size_t r0 = ((size_t)blockIdx.x*NCHUNK + ch)*CHUNK;
        // --- LN1 straight from global, split bf16 into LDS; 2 passes of 64 rows ---
        #pragma unroll
        for (int pp = 0; pp < 2; ++pp) {
            const int row = pp*64 + myrow;
            float v[16];
            #pragma unroll
            for (int j = 0; j < 4; ++j) {
                const f4v t = ntload4(x + (r0 + row)*DIM + lp*16 + j*4);
                v[j*4+0] = t[0]; v[j*4+1] = t[1]; v[j*4+2] = t[2]; v[j*4+3] = t[3];
            }
            float s = 0.f, q = 0.f;
            #pragma unroll
            for (int i = 0; i < 16; ++i) { s += v[i]; q += v[i]*v[i]; }
            #pragma unroll
            for (int o = 8; o < 64; o <<= 1) { s += __shfl_xor(s, o); q += __shfl_xor(q, o); }
            const float m  = s * (1.0f/128.0f);
            const float rs = rsqrtf(q * (1.0f/128.0f) - m*m + 1e-5f);
            unsigned short hi16[16], lo16[16];
            #pragma unroll
            for (int j = 0; j < 4; ++j) {
                const float4 g = *(const float4*)(ga + lp*16 + j*4);
                const float4 b = *(const float4*)(be + lp*16 + j*4);
                float hv0 = (v[j*4+0]-m)*rs*g.x + b.x;
                float hv1 = (v[j*4+1]-m)*rs*g.y + b.y;
                float hv2 = (v[j*4+2]-m)*rs*g.z + b.z;
                float hv3 = (v[j*4+3]-m)*rs*g.w + b.w;
                hi16[j*4+0] = f2bf(hv0); lo16[j*4+0] = f2bf(hv0 - bf2f(hi16[j*4+0]));
                hi16[j*4+1] = f2bf(hv1); lo16[j*4+1] = f2bf(hv1 - bf2f(hi16[j*4+1]));
                hi16[j*4+2] = f2bf(hv2); lo16[j*4+2] = f2bf(hv2 - bf2f(hi16[j*4+2]));
                hi16[j*4+3] = f2bf(hv3); lo16[j*4+3] = f2bf(hv3 - bf2f(hi16[j*4+3]));
            }
            #pragma unroll
            for (int j = 0; j < 2; ++j) {
                *(s8v*)&hh[row*SH + lp*16 + j*8] = *(const s8v*)&hi16[j*8];
                *(s8v*)&hl[row*SH + lp*16 + j*8] = *(const s8v*)&lo16[j*8];
            }
        }
        __syncthreads();
        // --- K and V projections: M=128, N=128, K=128; wave wv -> cols [wv*16,+16) ---
        #pragma unroll
        for (int p = 0; p < 2; ++p) {
            const s8v* bf = p ? bfV : bfK;
            unsigned short* T = p ? VT : KT;
            #pragma unroll
            for (int mt = 0; mt < 8; ++mt) {
                s8v ah[4], al[4];
                #pragma unroll
                for (int ks = 0; ks < 4; ++ks) {
                    ah[ks] = *(const s8v*)(&hh[(mt*16 + l15)*SH + ks*32 + quad*8]);
                    al[ks] = *(const s8v*)(&hl[(mt*16 + l15)*SH + ks*32 + quad*8]);
                }
                f4v c = {0.f,0.f,0.f,0.f};
                #pragma unroll
                for (int ks = 0; ks < 4; ++ks) c = MFMA16(ah[ks], bf[ks], c);
                #pragma unroll
                for (int ks = 0; ks < 4; ++ks) c = MFMA16(al[ks], bf[ks], c);
                // C layout: row=quad*4+reg, col=l15 -> store transposed T[col][row]
                u16x4 w4 = { f2bf(c[0]), f2bf(c[1]), f2bf(c[2]), f2bf(c[3]) };
                *(u16x4*)&T[pc*SH + mt*16 + quad*4] = w4;
            }
        }
        __syncthreads();
        // --- KtV += K_chunk^T @ V_chunk: M=128(i), N=128(j), K=128(rows) ---
        #pragma unroll
        for (int ks = 0; ks < 4; ++ks) {
            const s8v af = *(const s8v*)(&KT[pc*SH + ks*32 + quad*8]);
            #pragma unroll
            for (int jt = 0; jt < 8; ++jt) {
                const s8v bfr = *(const s8v*)(&VT[(jt*16 + l15)*SH + ks*32 + quad*8]);
                acc[jt] = MFMA16(af, bfr, acc[jt]);
            }
        }
        __syncthreads();
    }
    // --- accumulate partial KtV into one of NSLOT slots (fp32 atomics) ---
    float* S = slots + (size_t)(blockIdx.x & (NSLOT-1)) * 16384;
    #pragma unroll
    for (int jt = 0; jt < 8; ++jt) {
        const int i0 = wv*16 + quad*4;
        const int j  = jt*16 + l15;
        #pragma unroll
        for (int rg = 0; rg < 4; ++rg)
            atomicAdd(&S[(i0 + rg)*DIM + j], acc[jt][rg]);
    }
}

// Reduce NSLOT partial KtV matrices -> ktv (fp32, 128x128)
__global__ void kReduce(const float* __restrict__ slots, float* __restrict__ ktv)
{
    const int e = blockIdx.x*256 + threadIdx.x;  // 16384 threads
    float s = 0.f;
    #pragma unroll
    for (int b = 0; b < NSLOT; ++b) s += slots[(size_t)b*16384 + e];
    ktv[e] = s;
}

// M = Qw @ KtV (fp32), packed split bf16 as Mp/Ml[j][k] (B-operand [n][k] layout)
__global__ void kBuildM(const float* __restrict__ Qw, const float* __restrict__ ktv,
                        unsigned short* __restrict__ Mp, unsigned short* __restrict__ Ml)
{
    const int idx = blockIdx.x*256 + threadIdx.x;  // 16384
    const int j = idx >> 7, k = idx & 127;
    float s = 0.f;
    for (int i = 0; i < 128; ++i) s += Qw[k*128 + i] * ktv[i*128 + j];
    const unsigned short hi = f2bf(s);
    Mp[idx] = hi;
    Ml[idx] = f2bf(s - bf2f(hi));
}

// ---------------------------------------------------------------------------
// Kernel B: x += h1 @ M ; LN2 ; x += relu(h2@w1+b1)@w2 + b2   (in-place safe)
// CHUNK=128, 2 chunks/block. Mp/Ml fragments hoisted out of the chunk loop
// (read once per block). LDS 137 KB -> 1 block/CU, 8 waves.
// ---------------------------------------------------------------------------
__global__ __launch_bounds__(512, 2)
void kB(const float* __restrict__ xin, float* __restrict__ xout,
        const unsigned short* __restrict__ Mp, const unsigned short* __restrict__ Ml,
        const float* __restrict__ g1a, const float* __restrict__ b1a,
        const float* __restrict__ g2a, const float* __restrict__ b2a,
        const unsigned short* __restrict__ w1p, const float* __restrict__ fb1,
        const unsigned short* __restrict__ w2p, const float* __restrict__ fb2)
{
    __shared__ float          xb[128*132];  // fp32 residual tile, stride 132 (67.6 KB)
    __shared__ unsigned short hs[128*SH];   // bf16 LN output (hi)      (34.8 KB)
    __shared__ unsigned short fbuf[128*SH]; // relu(ff) quarter / h1-lo (34.8 KB)
    unsigned short* const hl = fbuf;
    const int tid  = threadIdx.x;
    const int wv   = tid >> 6, lane = tid & 63;
    const int quad = lane >> 4, l15 = lane & 15;
    const int lp   = lane >> 3, lr = lane & 7;
    const int myrow = wv*8 + lr;         // LN row (0..63), 2 passes
    const int cg    = wv*16 + l15;       // GEMM output col

    // --- M fragments: loaded once per block, live in registers ---
    s8v bh[4], bl[4];
    #pragma unroll
    for (int ks = 0; ks < 4; ++ks) {
        bh[ks] = *(const s8v*)(Mp + cg*DIM + ks*32 + quad*8);
        bl[ks] = *(const s8v*)(Ml + cg*DIM + ks*32 + quad*8);
    }

    for (int ch = 0; ch < NCHUNK; ++ch) {
        const size_t r0 = ((size_t)blockIdx.x*NCHUNK + ch)*CHUNK;
        // --- stage x chunk into LDS (coalesced non-temporal float4) ---
        #pragma unroll
        for (int i = 0; i < 8; ++i) {
            const int idx = tid + i*512;          // float4 index; 32 per row
            const int r = idx >> 5, c = (idx & 31)*4;
            const f4v t = ntload4(xin + (r0 + r)*DIM + c);
            *(f4v*)&xb[r*132 + c] = t;
        }
        __syncthreads();
        // --- LN1 (split), 16 elems/lane, 2 passes of 64 rows ---
        #pragma unroll
        for (int pp = 0; pp < 2; ++pp) {
            const int row = pp*64 + myrow;
            float v[16];
            #pragma unroll
            for (int j = 0; j < 4; ++j)
                *(float4*)&v[j*4] = *(const float4*)&xb[row*132 + lp*16 + j*4];
            float s = 0.f, q = 0.f;
            #pragma unroll
            for (int i = 0; i < 16; ++i) { s += v[i]; q += v[i]*v[i]; }
            #pragma unroll
            for (int o = 8; o < 64; o <<= 1) { s += __shfl_xor(s, o); q += __shfl_xor(q, o); }
            const float m  = s * (1.0f/128.0f);
            const float rs = rsqrtf(q * (1.0f/128.0f) - m*m + 1e-5f);
            unsigned short hi16[16], lo16[16];
            #pragma unroll
            for (int j = 0; j < 4; ++j) {
                const float4 g = *(const float4*)(g1a + lp*16 + j*4);
                const float4 b = *(const float4*)(b1a + lp*16 + j*4);
                float hv0 = (v[j*4+0]-m)*rs*g.x + b.x;
                float hv1 = (v[j*4+1]-m)*rs*g.y + b.y;
                float hv2 = (v[j*4+2]-m)*rs*g.z + b.z;
                float hv3 = (v[j*4+3]-m)*rs*g.w + b.w;
                hi16[j*4+0] = f2bf(hv0); lo16[j*4+0] = f2bf(hv0 - bf2f(hi16[j*4+0]));
                hi16[j*4+1] = f2bf(hv1); lo16[j*4+1] = f2bf(hv1 - bf2f(hi16[j*4+1]));
                hi16[j*4+2] = f2bf(hv2); lo16[j*4+2] = f2bf(hv2 - bf2f(hi16[j*4+2]));
                hi16[j*4+3] = f2bf(hv3); lo16[j*4+3] = f2bf(hv3 - bf2f(hi16[j*4+3]));
            }
            #pragma unroll
            for (int j = 0; j < 2; ++j) {
                *(s8v*)&hs[row*SH + lp*16 + j*8] = *(const s8v*)&hi16[j*8];
                *(s8v*)&hl[row*SH + lp*16 + j*8] = *(const s8v*)&lo16[j*8];
            }
        }
        __syncthreads();
        // --- GEMM1: dx = h1 @ M (3-way split), M fragments from registers ---
        #pragma unroll
        for (int mt = 0; mt < 8; ++mt) {
            s8v ah[4], al[4];
            #pragma unroll
            for (int ks = 0; ks < 4; ++ks) {
                ah[ks] = *(const s8v*)(&hs[(mt*16 + l15)*SH + ks*32 + quad*8]);
                al[ks] = *(const s8v*)(&hl[(mt*16 + l15)*SH + ks*32 + quad*8]);
            }
            f4v c = {0.f,0.f,0.f,0.f};
            #pragma unroll
            for (int ks = 0; ks < 4; ++ks) c = MFMA16(ah[ks], bh[ks], c);
            #pragma unroll
            for (int ks = 0; ks < 4; ++ks) c = MFMA16(ah[ks], bl[ks], c);
            #pragma unroll
            for (int ks = 0; ks < 4; ++ks) c = MFMA16(al[ks], bh[ks], c);
            #pragma unroll
            for (int rg = 0; rg < 4; ++rg)
                xb[(mt*16 + quad*4 + rg)*132 + cg] += c[rg];
        }
        __syncthreads();
        // --- LN2 (hi only), 2 passes ---
        #pragma unroll
        for (int pp = 0; pp < 2; ++pp) {
            const int row = pp*64 + myrow;
            float v[16];
            #pragma unroll
            for (int j = 0; j < 4; ++j)
                *(float4*)&v[j*4] = *(const float4*)&xb[row*132 + lp*16 + j*4];
            float s = 0.f, q = 0.f;
            #pragma unroll
            for (int i = 0; i < 16; ++i) { s += v[i]; q += v[i]*v[i]; }
            #pragma unroll
            for (int o = 8; o < 64; o <<= 1) { s += __shfl_xor(s, o); q += __shfl_xor(q, o); }
            const float m  = s * (1.0f/128.0f);
            const float rs = rsqrtf(q * (1.0f/128.0f) - m*m + 1e-5f);
            unsigned short hi16[16];
            #pragma unroll
            for (int j = 0; j < 4; ++j) {
                const float4 g = *(const float4*)(g2a + lp*16 + j*4);
                const float4 b = *(const float4*)(b2a + lp*16 + j*4);
                hi16[j*4+0] = f2bf((v[j*4+0]-m)*rs*g.x + b.x);
                hi16[j*4+1] = f2bf((v[j*4+1]-m)*rs*g.y + b.y);
                hi16[j*4+2] = f2bf((v[j*4+2]-m)*rs*g.z + b.z);
                hi16[j*4+3] = f2bf((v[j*4+3]-m)*rs*g.w + b.w);
            }
            #pragma unroll
            for (int j = 0; j < 2; ++j)
                *(s8v*)&hs[row*SH + lp*16 + j*8] = *(const s8v*)&hi16[j*8];
        }
        __syncthreads();
        // --- FF: four quarters of 128 ff-cols; dx2 accumulated across quarters ---
        f4v dx2[8];
        #pragma unroll
        for (int i = 0; i < 8; ++i) dx2[i] = (f4v){0.f,0.f,0.f,0.f};
        #pragma unroll
        for (int qf = 0; qf < 4; ++qf) {
            // GEMM2a: f = relu(h2 @ w1[:, quarter] + b1)
            const int ffc = qf*128 + cg;
            s8v wa[4];
            #pragma unroll
            for (int ks = 0; ks < 4; ++ks)
                wa[ks] = *(const s8v*)(w1p + ffc*DIM + ks*32 + quad*8);
            const float bias = fb1[ffc];
            #pragma unroll
            for (int mt = 0; mt < 8; ++mt) {
                s8v af[4];
                #pragma unroll
                for (int ks = 0; ks < 4; ++ks)
                    af[ks] = *(const s8v*)(&hs[(mt*16 + l15)*SH + ks*32 + quad*8]);
                f4v c = {0.f,0.f,0.f,0.f};
                #pragma unroll
                for (int ks = 0; ks < 4; ++ks) c = MFMA16(af[ks], wa[ks], c);
                #pragma unroll
                for (int rg = 0; rg < 4; ++rg) {
                    float vv = c[rg] + bias;
                    vv = vv > 0.f ? vv : 0.f;
                    fbuf[(mt*16 + quad*4 + rg)*SH + cg] = f2bf(vv);
                }
            }
            __syncthreads();
            // GEMM2b: dx2 += f @ w2[quarter, :]
            s8v wb[4];
            #pragma unroll
            for (int ks = 0; ks < 4; ++ks)
                wb[ks] = *(const s8v*)(w2p + cg*FFD + qf*128 + ks*32 + quad*8);
            #pragma unroll
            for (int mt = 0; mt < 8; ++mt) {
                s8v af[4];
                #pragma unroll
                for (int ks = 0; ks < 4; ++ks)
                    af[ks] = *(const s8v*)(&fbuf[(mt*16 + l15)*SH + ks*32 + quad*8]);
                f4v c = dx2[mt];
                #pragma unroll
                for (int ks = 0; ks < 4; ++ks) c = MFMA16(af[ks], wb[ks], c);
                dx2[mt] = c;
            }
            __syncthreads();
        }
        // --- epilogue: xb += dx2 + b2 ---
        {
            const float bias = fb2[cg];
            #pragma unroll
            for (int mt = 0; mt < 8; ++mt)
                #pragma unroll
                for (int rg = 0; rg < 4; ++rg)
                    xb[(mt*16 + quad*4 + rg)*132 + cg] += dx2[mt][rg] + bias;
        }
        __syncthreads();
        // --- coalesced non-temporal store (in-place safe) ---
        #pragma unroll
        for (int i = 0; i < 8; ++i) {
            const int idx = tid + i*512;
            const int r = idx >> 5, c = (idx & 31)*4;
            ntstore4(xout + (r0 + r)*DIM + c, *(const f4v*)&xb[r*132 + c]);
        }
        __syncthreads();
    }
}

// ---------------------------------------------------------------------------
// Final: out = x @ out_w + out_b  (split-x, in-place safe on d_out).
// Owp fragments hoisted out of the chunk loop.
// ---------------------------------------------------------------------------
#define CHUNKF 64
#define NCHUNKF 4
static_assert((long)NBLK * CHUNKF * NCHUNKF == NROWS, "kF grid mismatch");

__global__ __launch_bounds__(256, 2)
void kF(const float* __restrict__ x, const unsigned short* __restrict__ Owp,
        const float* __restrict__ ob, float* __restrict__ out)
{
    __shared__ unsigned short hh[64*SH];
    __shared__ unsigned short hl[64*SH];
    __shared__ float          xb[64*132];
    const int tid  = threadIdx.x;
    const int quad = (tid & 63) >> 4, l15 = tid & 15;
    const int wv_  = tid >> 6;

    s8v bf[2][4];
    #pragma unroll
    for (int nt = 0; nt < 2; ++nt)
        #pragma unroll
        for (int ks = 0; ks < 4; ++ks)
            bf[nt][ks] = *(const s8v*)(Owp + (wv_*32 + nt*16 + l15)*DIM + ks*32 + quad*8);

    for (int ch = 0; ch < NCHUNKF; ++ch) {
        const size_t r0 = ((size_t)blockIdx.x*NCHUNKF + ch)*CHUNKF;
        #pragma unroll
        for (int i = 0; i < 8; ++i) {
            const int idx = tid + i*256;
            const int r = idx >> 5, c = (idx & 31)*4;
            const f4v v = ntload4(x + (r0 + r)*DIM + c);
            const unsigned short h0 = f2bf(v[0]), h1 = f2bf(v[1]),
                                 h2 = f2bf(v[2]), h3 = f2bf(v[3]);
            u16x4 w4 = { h0, h1, h2, h3 };
            u16x4 l4 = { f2bf(v[0] - bf2f(h0)), f2bf(v[1] - bf2f(h1)),
                         f2bf(v[2] - bf2f(h2)), f2bf(v[3] - bf2f(h3)) };
            *(u16x4*)&hh[r*SH + c] = w4;
            *(u16x4*)&hl[r*SH + c] = l4;
        }
        __syncthreads();
        #pragma unroll
        for (int mt = 0; mt < 4; ++mt) {
            s8v ah[4], al[4];
            #pragma unroll
            for (int ks = 0; ks < 4; ++ks) {
                ah[ks] = *(const s8v*)(&hh[(mt*16 + l15)*SH + ks*32 + quad*8]);
                al[ks] = *(const s8v*)(&hl[(mt*16 + l15)*SH + ks*32 + quad*8]);
            }
            #pragma unroll
            for (int nt = 0; nt < 2; ++nt) {
                f4v c = {0.f,0.f,0.f,0.f};
                #pragma unroll
                for (int ks = 0; ks < 4; ++ks) c = MFMA16(ah[ks], bf[nt][ks], c);
                #pragma unroll
                for (int ks = 0; ks < 4; ++ks) c = MFMA16(al[ks], bf[nt][ks], c);
                const int cg = wv_*32 + nt*16 + l15;
                const float bias = ob[cg];
                #pragma unroll
                for (int rg = 0; rg < 4; ++rg)
                    xb[(mt*16 + quad*4 + rg)*132 + cg] = c[rg] + bias;
            }
        }
        __syncthreads();
        #pragma unroll
        for (int i = 0; i < 8; ++i) {
            const int idx = tid + i*256;
            const int r = idx >> 5, c = (idx & 31)*4;
            ntstore4(out + (r0 + r)*DIM + c, *(const f4v*)&xb[r*132 + c]);
        }
        __syncthreads();
    }
}

// Pack weights to bf16, transposed to B-operand-friendly [n][k] layout.
__global__ void kPack(const float* __restrict__ Kw, const float* __restrict__ Vw,
                      const float* __restrict__ Ow, const float* __restrict__ w1,
                      const float* __restrict__ w2,
                      unsigned short* __restrict__ Kwp, unsigned short* __restrict__ Vwp,
                      unsigned short* __restrict__ Owp, unsigned short* __restrict__ w1p,
                      unsigned short* __restrict__ w2p)
{
    const int t = blockIdx.x*256 + threadIdx.x;  // 147456 total
    if (t < 16384) {
        const int n = t >> 7, k = t & 127;
        Kwp[t] = f2bf(Kw[k*128 + n]);
        Vwp[t] = f2bf(Vw[k*128 + n]);
        Owp[t] = f2bf(Ow[k*128 + n]);
    } else if (t < 16384 + 65536) {
        const int u = t - 16384;
        const int n = u >> 7, k = u & 127;      // w1: [128][512] -> w1p[n<512][k<128]
        w1p[u] = f2bf(w1[k*FFD + n]);
    } else {
        const int u = t - 16384 - 65536;
        const int n = u >> 9, k = u & 511;      // w2: [512][128] -> w2p[n<128][k<512]
        w2p[u] = f2bf(w2[k*DIM + n]);
    }
}

extern "C" void kernel_launch(void* const* d_in, const int* in_sizes, int n_in,
                              void* d_out, int out_size, void* d_ws, size_t ws_size,
                              hipStream_t stream)
{
    (void)in_sizes; (void)n_in; (void)out_size; (void)ws_size;
    const float* x_in = (const float*)d_in[0];
    const float* Kw   = (const float*)d_in[1];
    const float* Qw   = (const float*)d_in[2];
    const float* Vw   = (const float*)d_in[3];
    const float* ln1g = (const float*)d_in[4];
    const float* ln1b = (const float*)d_in[5];
    const float* ln2g = (const float*)d_in[6];
    const float* ln2b = (const float*)d_in[7];
    const float* w1   = (const float*)d_in[8];
    const float* b1   = (const float*)d_in[9];
    const float* w2   = (const float*)d_in[10];
    const float* b2   = (const float*)d_in[11];
    const float* Ow   = (const float*)d_in[12];
    const float* ob   = (const float*)d_in[13];

    // Workspace (~1.5 MiB, known-safe single-copy layout).
    char* p = (char*)d_ws;
    float* slots        = (float*)p;          p += (size_t)NSLOT*16384*4;
    float* ktv          = (float*)p;          p += 16384*4;
    unsigned short* Kwp = (unsigned short*)p; p += 16384*2;
    unsigned short* Vwp = (unsigned short*)p; p += 16384*2;
    unsigned short* Owp = (unsigned short*)p; p += 16384*2;
    unsigned short* w1p = (unsigned short*)p; p += 65536*2;
    unsigned short* w2p = (unsigned short*)p; p += 65536*2;
    unsigned short* Mp  = (unsigned short*)p; p += 16384*2;
    unsigned short* Ml  = (unsigned short*)p; p += 16384*2;

    float* X = (float*)d_out;   // 131072 x 128 fp32 working buffer == output buffer

    kPack<<<576, 256, 0, stream>>>(Kw, Vw, Ow, w1, w2, Kwp, Vwp, Owp, w1p, w2p);

    const float* src = x_in;
    for (int t = 0; t < TSTEPS; ++t) {
        hipMemsetAsync(slots, 0, (size_t)NSLOT*16384*4, stream);
        kA<<<NBLK, 512, 0, stream>>>(src, Kwp, Vwp, ln1g, ln1b, slots);
        kReduce<<<64, 256, 0, stream>>>(slots, ktv);
        kBuildM<<<64, 256, 0, stream>>>(Qw, ktv, Mp, Ml);
        kB<<<NBLK, 512, 0, stream>>>(src, X, Mp, Ml, ln1g, ln1b, ln2g, ln2b,
                                     w1p, b1, w2p, b2);
        src = X;
    }
    kF<<<NBLK, 256, 0, stream>>>(X, Owp, ob, (float*)d_out);
}